// Round 7
// baseline (131.513 us; speedup 1.0000x reference)
//
#include <hip/hip_runtime.h>
#include <hip/hip_bf16.h>

// EdgeNetwork fused, round 7: round-5 structure + GRID 512 (2 blocks/CU).
//   out[src[e], i] += sum_{b,j} bond[e,b] * nb[e,j] * K[b, i*64+j]  (+ bias as ch 16)
// 8 waves = q(K quarter: 5 bond channels, padded 17->20) x h(N-half).
// W frags (20 x bf16x8 = 80 VGPR) loaded once from global (L2-resident).
// Per iter: stage next tile (double-buffered LDS), build bf16 A frags from
// reg-resident nb row x bond, 20 MFMAs in 2 chains; q1..3 write f32 partials
// to LDS, q0 combines + coalesced atomicAdd. ONE barrier/iter.
// GRID=512: 2 blocks/CU (LDS 2x70912=141824 <= 163840, VGPR 104 <= 128 -> 16 waves/CU)
// so one block's compute hides the other's barrier/memory drains.

#define N_EDGES   100000
#define DIM       64
#define BDIM      16
#define TILE      32
#define NTILES    (N_EDGES / TILE)      // 3125
#define BLOCK     512
#define GRID      512
#define NKS       20                    // 5 channels x 4 ksteps per wave

// ---- LDS map: NB f32[32][64] swizzled, BOND f32[32][20], SRC int[32], COMB f32[16][64] ----
#define NB_OFF(p)        ((p) * 8192)                                  // [0, 16384)
#define BOND_OFF(p)      (16384 + (p) * 2560)                          // [16384, 21504)
#define SRC_OFF(p)       (21504 + (p) * 128)                           // [21504, 21760)
#define COMB_OFF(p,h,qq) (21760 + ((((p)*2+(h))*3)+(qq)) * 4096)       // [21760, 70912)
#define LDS_TOTAL        70912

typedef __bf16 bf16x8 __attribute__((ext_vector_type(8)));
typedef float  f32x16 __attribute__((ext_vector_type(16)));

__global__ __launch_bounds__(BLOCK, 2)   // VGPR cap 256; measured alloc 104 -> 16 waves/CU
void edge_mfma_kernel(const float* __restrict__ atom,
                      const float* __restrict__ bondf,
                      const int*   __restrict__ pair,
                      const float* __restrict__ kmat,
                      const float* __restrict__ bias,
                      float* __restrict__ out)
{
    extern __shared__ char smem[];
    const int tid = threadIdx.x;
    const int l   = tid & 63;
    const int wid = tid >> 6;
    const int q   = wid >> 1;          // K quarter 0..3 (channels q*5 .. q*5+4)
    const int h   = wid & 1;           // N-half
    const int ma  = l & 31;
    const int hi  = l >> 5;
    const int n   = h * 32 + (l & 31);

    // ---------- W fragments -> registers, straight from global ----------
    // wfr[ci*4+ss] lane l holds W[k = (q*5+ci)*64 + ss*16 + hi*8 + j][n], j=0..7
    bf16x8 wfr[NKS];
    #pragma unroll
    for (int ci = 0; ci < 5; ++ci) {
        const int c = q * 5 + ci;
        #pragma unroll
        for (int ss = 0; ss < 4; ++ss) {
            bf16x8 w;
            if (c < 17) {   // wave-uniform branch
                const float* src = (c < BDIM) ? (kmat + c * (DIM * DIM) + n * DIM + ss * 16 + hi * 8)
                                              : (bias + n * DIM + ss * 16 + hi * 8);
                float4 v0 = *(const float4*)(src);
                float4 v1 = *(const float4*)(src + 4);
                w[0] = (__bf16)v0.x; w[1] = (__bf16)v0.y; w[2] = (__bf16)v0.z; w[3] = (__bf16)v0.w;
                w[4] = (__bf16)v1.x; w[5] = (__bf16)v1.y; w[6] = (__bf16)v1.z; w[7] = (__bf16)v1.w;
            } else {        // padded channels 17..19
                #pragma unroll
                for (int j = 0; j < 8; ++j) w[j] = (__bf16)0.0f;
            }
            wfr[ci * 4 + ss] = w;
        }
    }

    // ---------- staging: one tile (32 edges), all 512 threads ----------
    auto stage = [&](int stile, int pbuf) {
        const int sm = tid >> 4, sp = tid & 15;   // 16 threads/row, float4 each
        const int e  = stile * TILE + sm;
        const int dst = pair[2 * e + 1];
        float4 v = *(const float4*)(atom + dst * DIM + sp * 4);
        float* nbb = (float*)(smem + NB_OFF(pbuf));
        *(float4*)(nbb + sm * 64 + ((sp ^ (sm & 7)) << 2)) = v;   // 16B-chunk XOR swizzle
        float* bb = (float*)(smem + BOND_OFF(pbuf));
        bb[sm * 20 + sp] = bondf[e * BDIM + sp];
        if (sp == 0) {
            bb[sm * 20 + 16] = 1.0f;                              // bias channel
            ((int*)(smem + SRC_OFF(pbuf)))[sm] = pair[2 * e];
        } else if (sp < 4) {
            bb[sm * 20 + 16 + sp] = 0.0f;                         // padded channels
        }
    };

    int tile = blockIdx.x;
    stage(tile, 0);
    __syncthreads();
    int p = 0;

    while (true) {
        const int  ntile = tile + GRID;
        const bool more  = (ntile < NTILES);      // block-uniform
        if (more) stage(ntile, p ^ 1);            // overlaps compute

        const float* nbb = (const float*)(smem + NB_OFF(p));
        const float* bb  = (const float*)(smem + BOND_OFF(p));

        // nb row -> 32 f32 regs (this lane's hi-half of each 16-wide kstep)
        float nbf[32];
        #pragma unroll
        for (int ss = 0; ss < 4; ++ss) {
            const int cb = ss * 4 + hi * 2;
            float4 u0 = *(const float4*)(nbb + ma * 64 + (((cb    ) ^ (ma & 7)) << 2));
            float4 u1 = *(const float4*)(nbb + ma * 64 + (((cb + 1) ^ (ma & 7)) << 2));
            nbf[ss*8+0] = u0.x; nbf[ss*8+1] = u0.y; nbf[ss*8+2] = u0.z; nbf[ss*8+3] = u0.w;
            nbf[ss*8+4] = u1.x; nbf[ss*8+5] = u1.y; nbf[ss*8+6] = u1.z; nbf[ss*8+7] = u1.w;
        }
        float bnd[5];
        #pragma unroll
        for (int ci = 0; ci < 5; ++ci) bnd[ci] = bb[ma * 20 + q * 5 + ci];  // cols 17..19 pre-zeroed

        f32x16 ac0, ac1;
        #pragma unroll
        for (int i = 0; i < 16; ++i) { ac0[i] = 0.0f; ac1[i] = 0.0f; }

        #pragma unroll
        for (int ks = 0; ks < NKS; ++ks) {
            const int ci = ks >> 2, ss = ks & 3;
            const float bv = bnd[ci];
            bf16x8 a;
            a[0] = (__bf16)(bv * nbf[ss*8+0]); a[1] = (__bf16)(bv * nbf[ss*8+1]);
            a[2] = (__bf16)(bv * nbf[ss*8+2]); a[3] = (__bf16)(bv * nbf[ss*8+3]);
            a[4] = (__bf16)(bv * nbf[ss*8+4]); a[5] = (__bf16)(bv * nbf[ss*8+5]);
            a[6] = (__bf16)(bv * nbf[ss*8+6]); a[7] = (__bf16)(bv * nbf[ss*8+7]);
            if (ks & 1) ac1 = __builtin_amdgcn_mfma_f32_32x32x16_bf16(a, wfr[ks], ac1, 0, 0, 0);
            else        ac0 = __builtin_amdgcn_mfma_f32_32x32x16_bf16(a, wfr[ks], ac0, 0, 0, 0);
        }
        #pragma unroll
        for (int r = 0; r < 16; ++r) ac0[r] += ac1[r];

        int oaddr[16];
        if (q == 0) {
            // pre-read srcs BEFORE the barrier (next stage overwrites this buffer)
            const int* sr = (const int*)(smem + SRC_OFF(p));
            #pragma unroll
            for (int r = 0; r < 16; ++r) {
                const int m = (r & 3) + 8 * (r >> 2) + 4 * hi;
                oaddr[r] = sr[m] * DIM + n;
            }
        } else {
            float* cbw = (float*)(smem + COMB_OFF(p, h, q - 1));
            #pragma unroll
            for (int r = 0; r < 16; ++r) cbw[r * 64 + l] = ac0[r];
        }

        __syncthreads();   // staging(p^1) done; partials(p) visible

        if (q == 0) {
            const float* c0 = (const float*)(smem + COMB_OFF(p, h, 0));
            const float* c1 = (const float*)(smem + COMB_OFF(p, h, 1));
            const float* c2 = (const float*)(smem + COMB_OFF(p, h, 2));
            #pragma unroll
            for (int r = 0; r < 16; ++r)
                atomicAdd(out + oaddr[r], ac0[r] + c0[r*64+l] + c1[r*64+l] + c2[r*64+l]);
        }
        if (!more) break;
        tile = ntile; p ^= 1;
    }
}

extern "C" void kernel_launch(void* const* d_in, const int* in_sizes, int n_in,
                              void* d_out, int out_size, void* d_ws, size_t ws_size,
                              hipStream_t stream)
{
    const float* atom  = (const float*)d_in[0];
    const float* bondf = (const float*)d_in[1];
    const int*   pair  = (const int*)  d_in[2];
    const float* kmat  = (const float*)d_in[3];
    const float* bias  = (const float*)d_in[4];
    float* out = (float*)d_out;

    hipFuncSetAttribute((const void*)edge_mfma_kernel,
                        hipFuncAttributeMaxDynamicSharedMemorySize, LDS_TOTAL);
    hipMemsetAsync(out, 0, (size_t)out_size * sizeof(float), stream);
    edge_mfma_kernel<<<GRID, BLOCK, LDS_TOTAL, stream>>>(atom, bondf, pair, kmat, bias, out);
}